// Round 1
// baseline (1027.103 us; speedup 1.0000x reference)
//
#include <hip/hip_runtime.h>

// Problem constants (from reference setup_inputs): x is (G, B, L, H) fp32.
constexpr int G = 16;
constexpr int B = 8;
constexpr int L = 2048;
constexpr int H = 768;
constexpr int H4 = H / 4;       // 192 float4 chunks per vector
constexpr int NTHREADS = H4;    // 192 threads = 3 waves
constexpr int NWAVES = NTHREADS / 64;

// One block per (g,l). scores[b] = dot(x_b, sum_c x_c) - 1; softmax over B;
// out = sum_b w_b * x_b. Single read of each input element.
__global__ __launch_bounds__(NTHREADS) void interbag_kernel(
    const float* __restrict__ x, float* __restrict__ out) {
    const int gl = blockIdx.x;          // gl = g*L + l
    const int t  = threadIdx.x;         // 0..191, one float4 chunk each

    const float4* __restrict__ xv = reinterpret_cast<const float4*>(x);
    // element (g,b,l,h) flat index = ((g*B + b)*L + l)*H + h
    // in float4 units: ((g*B + b)*L + l)*H4 + t
    const int g = gl / L;
    const int l = gl - g * L;
    const size_t base    = ((size_t)(g * B) * L + l) * H4 + t;
    const size_t strideB = (size_t)L * H4;   // per-bag stride (float4 units)

    // Load all 8 bag chunks into registers (coalesced 16B/lane).
    float4 v[B];
#pragma unroll
    for (int b = 0; b < B; ++b) {
        v[b] = xv[base + (size_t)b * strideB];
    }

    // Bag-sum chunk.
    float4 s = v[0];
#pragma unroll
    for (int b = 1; b < B; ++b) {
        s.x += v[b].x; s.y += v[b].y; s.z += v[b].z; s.w += v[b].w;
    }

    // Per-thread partial dot of each bag chunk with the sum chunk.
    float p[B];
#pragma unroll
    for (int b = 0; b < B; ++b) {
        p[b] = v[b].x * s.x + v[b].y * s.y + v[b].z * s.z + v[b].w * s.w;
    }

    // Wave-level butterfly-free shuffle reduce (width 64).
#pragma unroll
    for (int off = 32; off >= 1; off >>= 1) {
#pragma unroll
        for (int b = 0; b < B; ++b) {
            p[b] += __shfl_down(p[b], off, 64);
        }
    }

    __shared__ float red[NWAVES][B];
    const int wave = t >> 6;
    const int lane = t & 63;
    if (lane == 0) {
#pragma unroll
        for (int b = 0; b < B; ++b) red[wave][b] = p[b];
    }
    __syncthreads();

    // Every thread redundantly computes the 8-way softmax (broadcast LDS reads).
    float sc[B];
    float m = -1e30f;
#pragma unroll
    for (int b = 0; b < B; ++b) {
        float v0 = red[0][b];
#pragma unroll
        for (int w = 1; w < NWAVES; ++w) v0 += red[w][b];
        sc[b] = v0 - 1.0f;
        m = fmaxf(m, sc[b]);
    }
    float denom = 0.0f;
#pragma unroll
    for (int b = 0; b < B; ++b) {
        sc[b] = __expf(sc[b] - m);
        denom += sc[b];
    }
    const float inv = 1.0f / denom;

    // Weighted combine from registers; write coalesced float4.
    float4 o = make_float4(0.f, 0.f, 0.f, 0.f);
#pragma unroll
    for (int b = 0; b < B; ++b) {
        const float w = sc[b] * inv;
        o.x += w * v[b].x; o.y += w * v[b].y; o.z += w * v[b].z; o.w += w * v[b].w;
    }

    float4* __restrict__ ov = reinterpret_cast<float4*>(out);
    ov[(size_t)gl * H4 + t] = o;
}

extern "C" void kernel_launch(void* const* d_in, const int* in_sizes, int n_in,
                              void* d_out, int out_size, void* d_ws, size_t ws_size,
                              hipStream_t stream) {
    const float* x = (const float*)d_in[0];
    float* out = (float*)d_out;
    dim3 grid(G * L);   // 32768 blocks, one per (g,l)
    dim3 block(NTHREADS);
    interbag_kernel<<<grid, block, 0, stream>>>(x, out);
}